// Round 20
// baseline (215.343 us; speedup 1.0000x reference)
//
#include <hip/hip_runtime.h>

// LSTM decoder: B=1024, S=256, H=128, O=7, T=512
// gates = h @ (W_ih+W_hh).T + (b_ih+b_hh); c'=sig(f)c+sig(i)tanh(g);
// h'=sig(o)tanh(c'); pred = h' @ W_out.T + b_out
//
// Round 20 = round 19 (214.8us: int8 gate MFMAs, exp2-folded trans, dual
// i8/bf16 ring, batched bf16 pred, SB interleave, setprio stagger) + two
// exact critical-tail shaves:
//  - magic-number i8 quantize: fma(x*127, 1.5*2^23) puts the RNE-rounded
//    two's-complement byte in the float's low 8 bits (0x400000 === 0 mod
//    256, same binade -> exact); replaces mul+rndne+cvt with ONE fma
//  - so127 = 127*sig(o) computed on the (shorter) sig(o) chain, parallel
//    to sig(f)->c->tanh(c); after tc both stores fork with 1 op each

#define HH    128
#define SSEQ  256
#define TT    512
#define OO    7
#define RB    4
#define HSTR16 144            // bf16 ring row stride (shorts)
#define SLOT16 (RB * HSTR16)  // shorts per bf16 slot
#define HSTR8  160            // i8 ring row stride (bytes): rows 8-bank skew
#define SLOT8  (RB * HSTR8)   // bytes per i8 slot
#define RING  32
#define L2E   1.44269504f
#define QMAGIC 12582912.f     // 1.5 * 2^23

typedef __attribute__((ext_vector_type(8))) short short8;
typedef __attribute__((ext_vector_type(4))) float f32x4;
typedef __attribute__((ext_vector_type(4))) int   int4v;

#define SB() __builtin_amdgcn_sched_barrier(0)

__device__ __forceinline__ unsigned short f2bf(float x) {
    union { float f; unsigned u; } v; v.f = x;
    return (unsigned short)((v.u + 0x7FFF + ((v.u >> 16) & 1)) >> 16); // RNE
}
// sigmoid with pre-scaled argument: expects u = -x*log2e
__device__ __forceinline__ float sigm_pre(float u) {
    return __builtin_amdgcn_rcpf(1.f + __builtin_amdgcn_exp2f(u));
}
// tanh with pre-scaled argument: expects v = x*2*log2e
__device__ __forceinline__ float tanh_pre(float v) {
    const float r = __builtin_amdgcn_rcpf(__builtin_amdgcn_exp2f(v) + 1.f);
    return __builtin_fmaf(-2.f, r, 1.f);
}

__global__ void __launch_bounds__(512, 2)
lstm_decoder_kernel(const float* __restrict__ ctx,
                    const float* __restrict__ Wih,
                    const float* __restrict__ Whh,
                    const float* __restrict__ bih,
                    const float* __restrict__ bhh,
                    const float* __restrict__ Wout,
                    const float* __restrict__ bout,
                    float* __restrict__ out) {
    // dual h rings: i8 for gate MFMAs, bf16 for the batched pred phase
    __shared__ __align__(16) char            h8_ring[RING * SLOT8];     // 20 KB
    __shared__ __align__(16) unsigned short h16_ring[RING * SLOT16];    // 36 KB
    // W_out B-fragments, lane-indexed (conflict-free): [kt][lane][8]
    __shared__ __align__(16) unsigned short wo_frag[4][64][8];          // 4 KB
    __shared__ float red[8][4];   // h0 row-max reduction scratch

    const int tid  = threadIdx.x;
    const int lane = tid & 63;
    const int wave = tid >> 6;
    const int rowBase = blockIdx.x * RB;

    const int lo   = lane & 15;
    const int hi   = lane >> 4;        // 0..3: this lane's batch row AND k-slice
    const int col  = wave * 16 + lo;   // this lane's gate/h column (0..127)
    const int arw8 = lo >> 2;          // i8 A-row mapping: C rows 4hi+r -> row hi

    // folded biases for this lane's column
    const float bi  = bih[col]          + bhh[col];
    const float bf_ = bih[HH + col]     + bhh[HH + col];
    const float bg  = bih[2 * HH + col] + bhh[2 * HH + col];
    const float bo  = bih[3 * HH + col] + bhh[3 * HH + col];
    const float bo_pred = (lo < OO) ? bout[lo] : 0.f;

    // ---- int8 W fragments: gate g, row n = g*128 + wave*16 + lo.
    // Lane holds W[n][kt*64 + hi*16 .. +16] as 16 i8 (one int4v per kt).
    // Per-row symmetric scale: rowmax over all 128 k via shfl_xor(16,32).
    int4v wq[4][2];
    float scB[4];   // rowmax/(127*127): dequant factor (x mh0 at step 0)
#pragma unroll
    for (int g = 0; g < 4; ++g) {
        const int n = g * HH + wave * 16 + lo;
        float wv[32];
        float am = 0.f;
#pragma unroll
        for (int kt = 0; kt < 2; ++kt)
#pragma unroll
            for (int j = 0; j < 16; ++j) {
                const int k = kt * 64 + hi * 16 + j;
                const float w = Wih[(size_t)n * HH + k] + Whh[(size_t)n * HH + k];
                wv[kt * 16 + j] = w;
                am = fmaxf(am, fabsf(w));
            }
        am = fmaxf(am, __shfl_xor(am, 16));
        am = fmaxf(am, __shfl_xor(am, 32));
        am = fmaxf(am, 1e-20f);
        scB[g] = am * (1.f / 16129.f);
        const float inv = 127.f / am;
#pragma unroll
        for (int kt = 0; kt < 2; ++kt) {
            int4v b;
#pragma unroll
            for (int w2 = 0; w2 < 4; ++w2) {
                int word = 0;
#pragma unroll
                for (int b_ = 0; b_ < 4; ++b_) {
                    int q = (int)__builtin_rintf(wv[kt * 16 + w2 * 4 + b_] * inv);
                    q = q > 127 ? 127 : (q < -127 ? -127 : q);
                    word |= (q & 255) << (8 * b_);
                }
                b[w2] = word;
            }
            wq[g][kt] = b;
        }
    }

    // W_out bf16 B-fragments into LDS (wave 0)
    if (wave == 0) {
#pragma unroll
        for (int kt = 0; kt < 4; ++kt) {
            const int k0 = kt * 32 + hi * 8;
            short8 w;
#pragma unroll
            for (int j = 0; j < 8; ++j)
                w[j] = (lo < OO) ? (short)f2bf(Wout[(size_t)lo * HH + k0 + j]) : (short)0;
            *(short8*)&wo_frag[kt][lane][0] = w;
        }
    }

    // ---- h0 = context_seq[:, S-1, :]; per-row max for step-0 i8 scale ----
    const float v0 = ctx[(size_t)(rowBase + hi) * SSEQ * HH + (size_t)(SSEQ - 1) * HH + col];
    float am0 = fabsf(v0);
    am0 = fmaxf(am0, __shfl_xor(am0, 1));
    am0 = fmaxf(am0, __shfl_xor(am0, 2));
    am0 = fmaxf(am0, __shfl_xor(am0, 4));
    am0 = fmaxf(am0, __shfl_xor(am0, 8));
    if (lo == 0) red[wave][hi] = am0;
    __syncthreads();
    float mh0 = 1e-20f;
#pragma unroll
    for (int w2 = 0; w2 < 8; ++w2) mh0 = fmaxf(mh0, red[w2][hi]);
    // quantize h0 into ring slot 0 (both formats)
    h8_ring[hi * HSTR8 + col]   = (char)(int)__builtin_rintf(v0 * (127.f / mh0));
    h16_ring[hi * HSTR16 + col] = f2bf(v0);
    float c_st = 0.f;   // cell state for (row hi, col)
    __syncthreads();

    // pre-scaled loop-carried dequant/bias constants (exp2-domain):
    //   sigmoid gates (i,f,o): u = fma(acc, -dq*L2E, -b*L2E); sig = sigm_pre(u)
    //   tanh gate (g):         v = fma(acc, dq*2L2E, b*2L2E); tg = tanh_pre(v)
    // step 0 folds the h0 per-row scale mh0 into dq.
    float dqI = -scB[0] * mh0 * L2E, dqF = -scB[1] * mh0 * L2E;
    float dqG =  scB[2] * mh0 * 2.f * L2E, dqO = -scB[3] * mh0 * L2E;
    const float biS = -bi * L2E, bfS = -bf_ * L2E;
    const float bgS = bg * 2.f * L2E, boS = -bo * L2E;

    const bool late = (wave & 4) != 0;   // second wave on each SIMD

    for (int it = 0; it <= TT; ++it) {
        // ---- batched bf16 pred phase every 32 steps (round-14 verbatim) ----
        if (it >= 32 && (it & 31) == 0) {
            f32x4 accp = {bo_pred, bo_pred, bo_pred, bo_pred};
            const int pbase = (4 * wave + (lo >> 2)) * SLOT16 + (lo & 3) * HSTR16 + hi * 8;
#pragma unroll
            for (int kt = 0; kt < 4; ++kt) {
                const short8 a  = *(const short8*)&h16_ring[pbase + kt * 32];
                const short8 wp = *(const short8*)&wo_frag[kt][lane][0];
                accp = __builtin_amdgcn_mfma_f32_16x16x32_bf16(a, wp, accp, 0, 0, 0);
            }
            if (lo < OO) {
                const int sig = 4 * wave + hi;
                const int s   = sig ? (it - 33 + sig) : (it - 1);
#pragma unroll
                for (int r = 0; r < 4; ++r)
                    out[(size_t)(rowBase + r) * TT * OO + (size_t)s * OO + lo] = accp[r];
            }
            __syncthreads();   // pred reads done before slots get overwritten
        }

        if (it == TT) break;

        // ---- LSTM step: h_it -> h_{it+1}, int8 gate matmul ----
        const int ab8 = (it & 31) * SLOT8 + arw8 * HSTR8 + hi * 16;
        const int4v a8_0 = *(const int4v*)&h8_ring[ab8];
        const int4v a8_1 = *(const int4v*)&h8_ring[ab8 + 64];

        int4v accI = {0, 0, 0, 0};
        int4v accG = {0, 0, 0, 0};
        int4v accF = {0, 0, 0, 0};
        int4v accO = {0, 0, 0, 0};

        // stagger: second wave on each SIMD takes pipe priority for its burst
        if (late) __builtin_amdgcn_s_setprio(1);

        // --- cluster I ---
        accI = __builtin_amdgcn_mfma_i32_16x16x64_i8(a8_0, wq[0][0], accI, 0, 0, 0);
        accI = __builtin_amdgcn_mfma_i32_16x16x64_i8(a8_1, wq[0][1], accI, 0, 0, 0);
        SB();
        // --- cluster G ---
        accG = __builtin_amdgcn_mfma_i32_16x16x64_i8(a8_0, wq[2][0], accG, 0, 0, 0);
        accG = __builtin_amdgcn_mfma_i32_16x16x64_i8(a8_1, wq[2][1], accG, 0, 0, 0);
        SB();
        // VALU chunk 1: sigmoid(i) in exp2 domain (acc[0] IS row hi)
        const float si_ = sigm_pre(__builtin_fmaf((float)accI[0], dqI, biS));
        SB();
        // --- cluster F ---
        accF = __builtin_amdgcn_mfma_i32_16x16x64_i8(a8_0, wq[1][0], accF, 0, 0, 0);
        accF = __builtin_amdgcn_mfma_i32_16x16x64_i8(a8_1, wq[1][1], accF, 0, 0, 0);
        SB();
        // VALU chunk 2: tanh(g), p = si*tg
        const float tg = tanh_pre(__builtin_fmaf((float)accG[0], dqG, bgS));
        const float p  = si_ * tg;
        SB();
        // --- cluster O ---
        accO = __builtin_amdgcn_mfma_i32_16x16x64_i8(a8_0, wq[3][0], accO, 0, 0, 0);
        accO = __builtin_amdgcn_mfma_i32_16x16x64_i8(a8_1, wq[3][1], accO, 0, 0, 0);
        if (late) __builtin_amdgcn_s_setprio(0);
        SB();
        // tail: sig(f)->c->tanh(c) chain runs parallel to sig(o)->so127;
        // after tc, the i8 store is ONE fma (magic) and the bf16 store one
        // mul + cvt_pk — shortest possible fork.
        const float sf_ = sigm_pre(__builtin_fmaf((float)accF[0], dqF, bfS));
        c_st = __builtin_fmaf(sf_, c_st, p);
        const float tc    = tanh_pre(c_st * (2.f * L2E));
        const float so_   = sigm_pre(__builtin_fmaf((float)accO[0], dqO, boS));
        const float so127 = so_ * 127.f;
        const float hnew  = so_ * tc;   // strictly in (-1,1)
        // magic-number quantize: low byte of (so127*tc + 1.5*2^23) is the
        // RNE-rounded two's-complement i8 (0x400000 === 0 mod 256, exact)
        const float qf = __builtin_fmaf(so127, tc, QMAGIC);

        const int dst = ((it + 1) & 31);
        h8_ring[dst * SLOT8 + hi * HSTR8 + col] = (char)__float_as_uint(qf);
        unsigned hpk;
        asm("v_cvt_pk_bf16_f32 %0, %1, %2" : "=v"(hpk) : "v"(hnew), "v"(hnew));
        h16_ring[dst * SLOT16 + hi * HSTR16 + col] = (unsigned short)hpk;

        // step-0 peel: drop the mh0 fold after the first iteration
        if (it == 0) {
            dqI = -scB[0] * L2E; dqF = -scB[1] * L2E;
            dqG =  scB[2] * 2.f * L2E; dqO = -scB[3] * L2E;
        }
        __syncthreads();
    }
}

extern "C" void kernel_launch(void* const* d_in, const int* in_sizes, int n_in,
                              void* d_out, int out_size, void* d_ws, size_t ws_size,
                              hipStream_t stream) {
    const float* ctx  = (const float*)d_in[0];
    const float* Wih  = (const float*)d_in[1];
    const float* Whh  = (const float*)d_in[2];
    const float* bih  = (const float*)d_in[3];
    const float* bhh  = (const float*)d_in[4];
    const float* Wout = (const float*)d_in[5];
    const float* bout = (const float*)d_in[6];
    float* out = (float*)d_out;

    lstm_decoder_kernel<<<dim3(1024 / RB), dim3(512), 0, stream>>>(
        ctx, Wih, Whh, bih, bhh, Wout, bout, out);
}